// Round 6
// baseline (451.666 us; speedup 1.0000x reference)
//
#include <hip/hip_runtime.h>
#include <stdint.h>

typedef __attribute__((ext_vector_type(8))) int i32x8;
typedef __attribute__((ext_vector_type(4))) float f32x4;

#define DIM 1024
#define NQ 4096
#define NDOC 8192
#define NKT 8           // K-tiles of 128

// ---------------- kernel 1: L2-normalize rows -> fp8 e4m3 (one wave per row) ------------
__global__ __launch_bounds__(256) void normalize_kernel(
    const float* __restrict__ q, const float* __restrict__ pos,
    const float* __restrict__ neg, uint8_t* __restrict__ qn8,
    uint8_t* __restrict__ dn8, float* __restrict__ rowsum) {
    int row = blockIdx.x * 4 + (threadIdx.x >> 6);
    int lane = threadIdx.x & 63;
    const float* src;
    uint8_t* dst;
    if (row < 4096) {
        src = q + (size_t)row * DIM; dst = qn8 + (size_t)row * DIM;
        if (lane == 0) rowsum[row] = 0.f;
    } else if (row < 8192) {
        src = pos + (size_t)(row - 4096) * DIM; dst = dn8 + (size_t)(row - 4096) * DIM;
    } else {
        src = neg + (size_t)(row - 8192) * DIM; dst = dn8 + (size_t)(row - 4096) * DIM;
    }
    float4 v[4];
    float ss = 0.f;
#pragma unroll
    for (int it = 0; it < 4; ++it) {
        v[it] = reinterpret_cast<const float4*>(src)[it * 64 + lane];
        ss += v[it].x * v[it].x + v[it].y * v[it].y + v[it].z * v[it].z + v[it].w * v[it].w;
    }
#pragma unroll
    for (int off = 32; off > 0; off >>= 1) ss += __shfl_xor(ss, off, 64);
    float inv = rsqrtf(ss);
#pragma unroll
    for (int it = 0; it < 4; ++it) {
        int b = __builtin_amdgcn_cvt_pk_fp8_f32(v[it].x * inv, v[it].y * inv, 0, false);
        b = __builtin_amdgcn_cvt_pk_fp8_f32(v[it].z * inv, v[it].w * inv, b, true);
        *reinterpret_cast<unsigned*>(dst + it * 256 + lane * 4) = (unsigned)b;
    }
}

// ---------------- kernel 2: 256x256 fp8-MX GEMM (K-instr=128) + fused exp-sum -----------
// LDS: 2 buffers x 64 KB. Buffer: A rows [256][128 B] at +0, B same at +32768.
// Swizzle: LDS[row][slot16] = G[row][slot ^ (row&7)]. Staging chunk c=r*512+tid:
// row=c>>3, slot=c&7, dest byte=c*16 (linear); 8 lanes/row -> 128 B/row full-line reads.
// Frag (lane lr,lk): 32 B = G slots {2lk,2lk+1} -> LDS slots {s,s^1} where s=(2lk)^(lr&7).
#define GLOAD_LDS(g, l) __builtin_amdgcn_global_load_lds( \
    (const __attribute__((address_space(1))) void*)(g),   \
    (__attribute__((address_space(3))) void*)(l), 16, 0, 0)

#define STG2(bufByte, kt, r) {                                              \
    GLOAD_LDS(aG + (r) * 65536 + (kt) * 128, ldsc + (bufByte) + ((r) * 512 + tid) * 16); \
    GLOAD_LDS(bG + (r) * 65536 + (kt) * 128, ldsc + (bufByte) + 32768 + ((r) * 512 + tid) * 16); \
  }

__device__ __forceinline__ i32x8 pack8(int4 lo, int4 hi) {
    i32x8 v;
    v[0] = lo.x; v[1] = lo.y; v[2] = lo.z; v[3] = lo.w;
    v[4] = hi.x; v[5] = hi.y; v[6] = hi.z; v[7] = hi.w;
    return v;
}

#define SC1 0x7F7F7F7F   // e8m0 scales = 1.0

__global__ __launch_bounds__(512, 1) void gemm_lse_kernel(
    const uint8_t* __restrict__ qn8, const uint8_t* __restrict__ dn8,
    float* __restrict__ rowsum, float* __restrict__ diag) {
    extern __shared__ char ldsc[];   // 131072 bytes
    const int tid = threadIdx.x;
    const int lane = tid & 63;
    const int wid = tid >> 6;
    const int wr = wid >> 2;        // 0..1  (128-row half)
    const int wc = wid & 3;         // 0..3  (64-col slice)
    const int lr = lane & 15;
    const int lk = lane >> 4;

    // XCD-aware blocked swizzle over the 16x32 tile grid
    int bid = blockIdx.x;
    int xcd = bid & 7, local = bid >> 3;
    int brow = (xcd >> 2) * 8 + (local >> 3);   // 0..15
    int bcol = (xcd & 3) * 8 + (local & 7);     // 0..31

    // staging source (slot pre-permuted within the 128 B line)
    const int srow = tid >> 3;                       // 0..63 (+ r*64)
    const int sslot = (tid & 7) ^ (srow & 7);
    const uint8_t* aG = qn8 + (size_t)(brow * 256 + srow) * DIM + sslot * 16;
    const uint8_t* bG = dn8 + (size_t)(bcol * 256 + srow) * DIM + sslot * 16;

    // fragment read bases (bytes); hi half = lo ^ 16
    const int s0 = ((lk * 2) ^ (lane & 7)) * 16;
    const int aB0 = (wr * 128 + lr) * 128 + s0;
    const int bB0 = 32768 + (wc * 64 + lr) * 128 + s0;

    f32x4 acc[8][4] = {};

    // prologue: tile 0 (rounds 0-3) into buf0, round 0 of tile 1 into buf1
#pragma unroll
    for (int r = 0; r < 4; ++r) STG2(0, 0, r);
    STG2(65536, 1, 0);
    asm volatile("s_waitcnt vmcnt(2)" ::: "memory");
    __builtin_amdgcn_s_barrier();

    for (int t = 0; t < NKT; ++t) {
        const int cur = (t & 1) ? 65536 : 0;
        const int nxt = cur ^ 65536;
        const bool st = t < NKT - 1;
        i32x8 bV[4], aV[4];
#pragma unroll
        for (int n = 0; n < 4; ++n) {
            int4 lo = *(const int4*)(ldsc + cur + bB0 + n * 2048);
            int4 hi = *(const int4*)(ldsc + cur + (bB0 ^ 16) + n * 2048);
            bV[n] = pack8(lo, hi);
        }
#pragma unroll
        for (int m = 0; m < 4; ++m) {
            int4 lo = *(const int4*)(ldsc + cur + aB0 + m * 2048);
            int4 hi = *(const int4*)(ldsc + cur + (aB0 ^ 16) + m * 2048);
            aV[m] = pack8(lo, hi);
        }
        if (st) { STG2(nxt, t + 1, 1); STG2(nxt, t + 1, 2); }
        __builtin_amdgcn_s_barrier();
        __builtin_amdgcn_s_setprio(1);
#pragma unroll
        for (int m = 0; m < 4; ++m)
#pragma unroll
            for (int n = 0; n < 4; ++n)
                acc[m][n] = __builtin_amdgcn_mfma_scale_f32_16x16x128_f8f6f4(
                    aV[m], bV[n], acc[m][n], 0, 0, 0, SC1, 0, SC1);
        __builtin_amdgcn_s_setprio(0);
        // phase B: second m-half
#pragma unroll
        for (int m = 0; m < 4; ++m) {
            int4 lo = *(const int4*)(ldsc + cur + aB0 + (m + 4) * 2048);
            int4 hi = *(const int4*)(ldsc + cur + (aB0 ^ 16) + (m + 4) * 2048);
            aV[m] = pack8(lo, hi);
        }
        if (st) STG2(nxt, t + 1, 3);
        __builtin_amdgcn_s_barrier();
        __builtin_amdgcn_s_setprio(1);
#pragma unroll
        for (int m = 0; m < 4; ++m)
#pragma unroll
            for (int n = 0; n < 4; ++n)
                acc[m + 4][n] = __builtin_amdgcn_mfma_scale_f32_16x16x128_f8f6f4(
                    aV[m], bV[n], acc[m + 4][n], 0, 0, 0, SC1, 0, SC1);
        __builtin_amdgcn_s_setprio(0);
        if (t < NKT - 2) {
            __builtin_amdgcn_s_barrier();      // all reads of cur drained
            STG2(cur, t + 2, 0);               // round 0 of tile t+2 into cur
            asm volatile("s_waitcnt vmcnt(2)" ::: "memory");  // tile t+1 landed
            __builtin_amdgcn_s_barrier();
        } else if (t == NKT - 2) {
            __builtin_amdgcn_s_barrier();
            asm volatile("s_waitcnt vmcnt(0)" ::: "memory");
            __builtin_amdgcn_s_barrier();
        }
    }

    // epilogue: rowsum[row] += sum_cols exp(20*s - 20); diag extraction on brow==bcol
    // C/D: col = wc*64 + n*16 + lr, row = wr*128 + m*16 + lk*4 + j (in-tile)
#pragma unroll
    for (int m = 0; m < 8; ++m) {
#pragma unroll
        for (int j = 0; j < 4; ++j) {
            float r = 0.f;
#pragma unroll
            for (int n = 0; n < 4; ++n) {
                float s = 20.f * acc[m][n][j] - 20.f;
                r += __expf(s);
            }
#pragma unroll
            for (int off = 1; off < 16; off <<= 1) r += __shfl_xor(r, off, 64);
            if (lr == 0) {
                int row = brow * 256 + wr * 128 + m * 16 + lk * 4 + j;
                atomicAdd(&rowsum[row], r);
            }
        }
    }
    if (brow == bcol) {
#pragma unroll
        for (int m = 0; m < 8; ++m)
#pragma unroll
            for (int j = 0; j < 4; ++j) {
                int tr = wr * 128 + m * 16 + lk * 4 + j;   // in-tile row
#pragma unroll
                for (int n = 0; n < 4; ++n)
                    if (wc * 64 + n * 16 + lr == tr)
                        diag[brow * 256 + tr] = 20.f * acc[m][n][j];
            }
    }
}

// ---------------- kernel 3: finalize  loss = mean(20 + log(rowsum) - diag) --------------
__global__ __launch_bounds__(1024) void finalize_kernel(
    const float* __restrict__ rowsum, const float* __restrict__ diag,
    float* __restrict__ out) {
    int t = threadIdx.x;
    float s = 0.f;
#pragma unroll
    for (int i = 0; i < 4; ++i) {
        int r = t + i * 1024;
        s += (20.f + __logf(rowsum[r])) - diag[r];
    }
#pragma unroll
    for (int off = 32; off > 0; off >>= 1) s += __shfl_xor(s, off, 64);
    __shared__ float wsum[16];
    if ((t & 63) == 0) wsum[t >> 6] = s;
    __syncthreads();
    if (t == 0) {
        float tot = 0.f;
#pragma unroll
        for (int i = 0; i < 16; ++i) tot += wsum[i];
        out[0] = tot * (1.f / 4096.f);
    }
}

extern "C" void kernel_launch(void* const* d_in, const int* in_sizes, int n_in,
                              void* d_out, int out_size, void* d_ws, size_t ws_size,
                              hipStream_t stream) {
    const float* q   = (const float*)d_in[0];
    const float* pos = (const float*)d_in[1];
    const float* neg = (const float*)d_in[2];
    float* out = (float*)d_out;
    char* ws = (char*)d_ws;
    uint8_t* qn8 = (uint8_t*)ws;                                   // 4 MB
    uint8_t* dn8 = (uint8_t*)(ws + (size_t)4 * 1024 * 1024);       // 8 MB
    float* rowsum = (float*)(ws + (size_t)12 * 1024 * 1024);       // 16 KB
    float* diag   = (float*)(ws + (size_t)12 * 1024 * 1024 + 16384); // 16 KB

    static bool attr_set = false;
    if (!attr_set) {
        (void)hipFuncSetAttribute((const void*)gemm_lse_kernel,
                                  hipFuncAttributeMaxDynamicSharedMemorySize, 131072);
        attr_set = true;
    }

    normalize_kernel<<<3072, 256, 0, stream>>>(q, pos, neg, qn8, dn8, rowsum);
    gemm_lse_kernel<<<512, 512, 131072, stream>>>(qn8, dn8, rowsum, diag);
    finalize_kernel<<<1, 1024, 0, stream>>>(rowsum, diag, out);
}

// Round 8
// 163.458 us; speedup vs baseline: 2.7632x; 2.7632x over previous
//
#include <hip/hip_runtime.h>
#include <stdint.h>

typedef __attribute__((ext_vector_type(8))) short s16x8;
typedef __attribute__((ext_vector_type(4))) float f32x4;

#define DIM 1024
#define NQ 4096
#define NDOC 8192
#define NKT 16          // K-tiles of 64

__device__ __forceinline__ unsigned f2bf(float f) {
    unsigned int u = __builtin_bit_cast(unsigned int, f);
    u += 0x7FFFu + ((u >> 16) & 1u);   // RNE
    return u >> 16;
}

// ---------------- kernel 1: L2-normalize rows -> bf16 (one wave per row) ----------------
__global__ __launch_bounds__(256) void normalize_kernel(
    const float* __restrict__ q, const float* __restrict__ pos,
    const float* __restrict__ neg, unsigned short* __restrict__ qn,
    unsigned short* __restrict__ dn, float* __restrict__ rowsum) {
    int row = blockIdx.x * 4 + (threadIdx.x >> 6);
    int lane = threadIdx.x & 63;
    const float* src;
    unsigned short* dst;
    if (row < 4096) {
        src = q + (size_t)row * DIM; dst = qn + (size_t)row * DIM;
        if (lane == 0) rowsum[row] = 0.f;
    } else if (row < 8192) {
        src = pos + (size_t)(row - 4096) * DIM; dst = dn + (size_t)(row - 4096) * DIM;
    } else {
        src = neg + (size_t)(row - 8192) * DIM; dst = dn + (size_t)(row - 4096) * DIM;
    }
    float4 v[4];
    float ss = 0.f;
#pragma unroll
    for (int it = 0; it < 4; ++it) {
        v[it] = reinterpret_cast<const float4*>(src)[it * 64 + lane];
        ss += v[it].x * v[it].x + v[it].y * v[it].y + v[it].z * v[it].z + v[it].w * v[it].w;
    }
#pragma unroll
    for (int off = 32; off > 0; off >>= 1) ss += __shfl_xor(ss, off, 64);
    float inv = rsqrtf(ss);
#pragma unroll
    for (int it = 0; it < 4; ++it) {
        uint2 o;
        o.x = f2bf(v[it].x * inv) | (f2bf(v[it].y * inv) << 16);
        o.y = f2bf(v[it].z * inv) | (f2bf(v[it].w * inv) << 16);
        reinterpret_cast<uint2*>(dst)[it * 64 + lane] = o;
    }
}

// ---------------- kernel 2: 256x256 GEMM, BK=64, 16 waves, coalesced swizzled staging ---
// LDS: 2 buffers x 64 KB. Buffer: A rows [256][64 bf16] at +0 (row stride 128 B),
// B same at +32768. Swizzle: LDS[row][slot16] = G[row][slot ^ (row&7)].
// Staging chunk c = r*1024+tid -> row=c>>3 (r adds 128), slot=c&7; dest byte=c*16
// (linear; wave = 8 rows x 128 B contiguous global per row -> full-line coalescing).
// Frag read: row = wr*64+m*16+lr, slot = (KS*4+lk) ^ (lr&7) -> 2-way bank alias (free).
#define GLOAD_LDS(g, l) __builtin_amdgcn_global_load_lds( \
    (const __attribute__((address_space(1))) void*)(g),   \
    (__attribute__((address_space(3))) void*)(l), 16, 0, 0)

#define STG2(bufByte, kt, r) {                                                        \
    GLOAD_LDS(aG + (r) * 131072 + (kt) * 64, ldsc + (bufByte) + ((r) * 1024 + tid) * 16); \
    GLOAD_LDS(bG + (r) * 131072 + (kt) * 64, ldsc + (bufByte) + 32768 + ((r) * 1024 + tid) * 16); \
  }

// phase: {frag reads ; optional staged loads ; barrier ; prio1 ; 16 MFMA ; prio0}
#define PHASE(CUR, KS, DOSTG, KT1) {                                              \
    s16x8 bF[4], aF[4];                                                           \
    _Pragma("unroll") for (int n = 0; n < 4; ++n)                                 \
        bF[n] = *(const s16x8*)(ldsc + (CUR) + (bB0 ^ ((KS) * 64)) + n * 2048);   \
    _Pragma("unroll") for (int m = 0; m < 4; ++m)                                 \
        aF[m] = *(const s16x8*)(ldsc + (CUR) + (aB0 ^ ((KS) * 64)) + m * 2048);   \
    if (DOSTG) STG2((CUR) ^ 65536, KT1, 1);                                       \
    __builtin_amdgcn_s_barrier();                                                 \
    __builtin_amdgcn_s_setprio(1);                                                \
    _Pragma("unroll") for (int m = 0; m < 4; ++m)                                 \
        _Pragma("unroll") for (int n = 0; n < 4; ++n)                             \
            acc[m][n] = __builtin_amdgcn_mfma_f32_16x16x32_bf16(                  \
                aF[m], bF[n], acc[m][n], 0, 0, 0);                                \
    __builtin_amdgcn_s_setprio(0);                                                \
  }

__global__ __launch_bounds__(1024, 4) void gemm_lse_kernel(
    const unsigned short* __restrict__ qn, const unsigned short* __restrict__ dn,
    float* __restrict__ rowsum, float* __restrict__ diag) {
    extern __shared__ char ldsc[];   // 131072 bytes
    const int tid = threadIdx.x;
    const int lane = tid & 63;
    const int wid = tid >> 6;       // 0..15
    const int wr = wid >> 2;        // 0..3  (64-row slice)
    const int wc = wid & 3;         // 0..3  (64-col slice)
    const int lr = lane & 15;
    const int lk = lane >> 4;

    // XCD-aware blocked swizzle over the 16x32 tile grid
    int bid = blockIdx.x;
    int xcd = bid & 7, local = bid >> 3;
    int brow = (xcd >> 2) * 8 + (local >> 3);   // 0..15
    int bcol = (xcd & 3) * 8 + (local & 7);     // 0..31

    // staging source (slot pre-permuted within the same 128 B line)
    const int srow = tid >> 3;                       // 0..127 (+ r*128)
    const int sslot = (tid & 7) ^ (srow & 7);
    const unsigned short* aG = qn + (size_t)(brow * 256 + srow) * DIM + sslot * 8;
    const unsigned short* bG = dn + (size_t)(bcol * 256 + srow) * DIM + sslot * 8;

    // fragment read bases (bytes); KS toggles bit 6 (slot ^= 4)
    const int s0 = lk ^ (lane & 7);
    const int aB0 = (wr * 64 + lr) * 128 + s0 * 16;
    const int bB0 = 32768 + (wc * 64 + lr) * 128 + s0 * 16;

    f32x4 acc[4][4] = {};

    // prologue: tile 0 (rounds 0-1) into buf0, round 0 of tile 1 into buf1
    STG2(0, 0, 0); STG2(0, 0, 1);
    STG2(65536, 1, 0);
    asm volatile("s_waitcnt vmcnt(2)" ::: "memory");   // tile 0 landed
    __builtin_amdgcn_s_barrier();

    for (int t = 0; t < NKT; ++t) {
        const int cur = (t & 1) ? 65536 : 0;
        const bool st = t < NKT - 1;
        PHASE(cur, 0, st, t + 1)
        PHASE(cur, 1, false, 0)
        if (t < NKT - 2) {
            __builtin_amdgcn_s_barrier();      // all reads of cur drained
            STG2(cur, t + 2, 0);               // round 0 of tile t+2 into cur
            asm volatile("s_waitcnt vmcnt(2)" ::: "memory");  // tile t+1 landed
            __builtin_amdgcn_s_barrier();
        } else if (t == NKT - 2) {
            __builtin_amdgcn_s_barrier();
            asm volatile("s_waitcnt vmcnt(0)" ::: "memory");
            __builtin_amdgcn_s_barrier();
        }
    }

    // epilogue: rowsum[row] += sum_cols exp(20*s - 20); diag on brow==bcol tiles
    // C/D: col = wc*64 + n*16 + lr, in-tile row = wr*64 + m*16 + lk*4 + j
#pragma unroll
    for (int m = 0; m < 4; ++m) {
#pragma unroll
        for (int j = 0; j < 4; ++j) {
            float r = 0.f;
#pragma unroll
            for (int n = 0; n < 4; ++n) {
                float s = 20.f * acc[m][n][j] - 20.f;
                r += __expf(s);
            }
#pragma unroll
            for (int off = 1; off < 16; off <<= 1) r += __shfl_xor(r, off, 64);
            if (lr == 0) {
                int row = brow * 256 + wr * 64 + m * 16 + lk * 4 + j;
                atomicAdd(&rowsum[row], r);
            }
        }
    }
    if (brow == bcol) {
#pragma unroll
        for (int m = 0; m < 4; ++m)
#pragma unroll
            for (int j = 0; j < 4; ++j) {
                int tr = wr * 64 + m * 16 + lk * 4 + j;   // in-tile row
#pragma unroll
                for (int n = 0; n < 4; ++n)
                    if (wc * 64 + n * 16 + lr == tr)
                        diag[brow * 256 + tr] = 20.f * acc[m][n][j];
            }
    }
}

// ---------------- kernel 3: finalize  loss = mean(20 + log(rowsum) - diag) --------------
__global__ __launch_bounds__(1024) void finalize_kernel(
    const float* __restrict__ rowsum, const float* __restrict__ diag,
    float* __restrict__ out) {
    int t = threadIdx.x;
    float s = 0.f;
#pragma unroll
    for (int i = 0; i < 4; ++i) {
        int r = t + i * 1024;
        s += (20.f + __logf(rowsum[r])) - diag[r];
    }
#pragma unroll
    for (int off = 32; off > 0; off >>= 1) s += __shfl_xor(s, off, 64);
    __shared__ float wsum[16];
    if ((t & 63) == 0) wsum[t >> 6] = s;
    __syncthreads();
    if (t == 0) {
        float tot = 0.f;
#pragma unroll
        for (int i = 0; i < 16; ++i) tot += wsum[i];
        out[0] = tot * (1.f / 4096.f);
    }
}

extern "C" void kernel_launch(void* const* d_in, const int* in_sizes, int n_in,
                              void* d_out, int out_size, void* d_ws, size_t ws_size,
                              hipStream_t stream) {
    const float* q   = (const float*)d_in[0];
    const float* pos = (const float*)d_in[1];
    const float* neg = (const float*)d_in[2];
    float* out = (float*)d_out;
    char* ws = (char*)d_ws;
    unsigned short* qn = (unsigned short*)ws;                                 // 8 MB
    unsigned short* dn = (unsigned short*)(ws + (size_t)8 * 1024 * 1024);     // 16 MB
    float* rowsum = (float*)(ws + (size_t)24 * 1024 * 1024);                  // 16 KB
    float* diag   = (float*)(ws + (size_t)24 * 1024 * 1024 + 16384);          // 16 KB

    static bool attr_set = false;
    if (!attr_set) {
        (void)hipFuncSetAttribute((const void*)gemm_lse_kernel,
                                  hipFuncAttributeMaxDynamicSharedMemorySize, 131072);
        attr_set = true;
    }

    normalize_kernel<<<3072, 256, 0, stream>>>(q, pos, neg, qn, dn, rowsum);
    gemm_lse_kernel<<<512, 1024, 131072, stream>>>(qn, dn, rowsum, diag);
    finalize_kernel<<<1, 1024, 0, stream>>>(rowsum, diag, out);
}